// Round 14
// baseline (3133.119 us; speedup 1.0000x reference)
//
#include <hip/hip_runtime.h>
#include <math.h>

#define N_NODES 40960
#define N_EDGES 655360
#define NPG     640
#define NGRAPH  64
#define EPG     10240   // edges per graph (E / NGRAPH, exact)
#define DH      128
#define NLAYERS 4
#define GATE_EPS 1e-6f
#define BN_EPS   1e-5f
#define ETPB    8     // egemm row-tiles (64 rows each) per block

// Static device scratch pool (module-load allocated; graph-capture safe).
#define POOL_BYTES 580000000ull
__device__ __attribute__((aligned(256))) unsigned char g_pool[POOL_BYTES];

using short8  = __attribute__((ext_vector_type(8))) short;
using float4v = __attribute__((ext_vector_type(4))) float;

static __device__ __forceinline__ float sigmoidf_(float x) {
  return 1.f / (1.f + __expf(-x));
}
static __device__ __forceinline__ unsigned short f2bf(float f) {
  unsigned int u = __float_as_uint(f);
  unsigned int r = 0x7FFFu + ((u >> 16) & 1u);
  return (unsigned short)((u + r) >> 16);
}
static __device__ __forceinline__ float bf2f(unsigned short h) {
  return __uint_as_float(((unsigned int)h) << 16);
}

// ---------------------------------------------------------------------------
// Edge-gate GEMM, CSR-ordered edges, ETPB 64-row tiles per block.
// hat[e,:] = bf16(ef@B3 + b3 + G1[src] + G2[dst])   (G1,G2 in bf16)
// W read DIRECT from L2 (no LDS staging; 32KB working set, shared by all
// blocks — pattern proven by ngemm6). LDS = hatB only (17.6KB) -> 6 blocks/CU.
// ---------------------------------------------------------------------------
template <int WITH_STATS>
__global__ __launch_bounds__(256)
void egemm(const unsigned short* __restrict__ ef,
           const unsigned short* __restrict__ Wt,
           const float* __restrict__ bias,
           unsigned short* __restrict__ hat,
           const int* __restrict__ srcp, const int* __restrict__ dstp,
           const unsigned short* __restrict__ G1, const unsigned short* __restrict__ G2,
           float* __restrict__ stats, float* __restrict__ ssum)
{
  __shared__ unsigned short hatB[64][136];
  __shared__ int dstL[64];

  const int t    = threadIdx.x;
  const int w    = t >> 6;
  const int lane = t & 63;
  const int quad = lane >> 4;
  const int l16  = lane & 15;
  const size_t base = (size_t)blockIdx.x * (64 * ETPB);
  const int er = t >> 2;                       // epilogue row 0..63

  // prefetch src/dst for this thread's epilogue rows, all tiles
  int sI[ETPB], dI[ETPB];
#pragma unroll
  for (int tl = 0; tl < ETPB; ++tl) {
    sI[tl] = srcp[base + tl * 64 + er];
    dI[tl] = dstp[base + tl * 64 + er];
  }

  float stat_s = 0.f, stat_q = 0.f;

  for (int tile = 0; tile < ETPB; ++tile) {
    const size_t row0 = base + tile * 64;

    // A fragments: direct global loads
    const size_t arow = row0 + w * 16 + l16;
    short8 a[4];
#pragma unroll
    for (int ks = 0; ks < 4; ++ks)
      a[ks] = *reinterpret_cast<const short8*>(&ef[arow * 128 + ks * 32 + quad * 8]);

    float4v acc[8];
#pragma unroll
    for (int j = 0; j < 8; ++j) acc[j] = (float4v){0.f, 0.f, 0.f, 0.f};
#pragma unroll
    for (int ks = 0; ks < 4; ++ks)
#pragma unroll
      for (int j = 0; j < 8; ++j) {
        short8 b = *reinterpret_cast<const short8*>(
            &Wt[(size_t)(j * 16 + l16) * 128 + ks * 32 + quad * 8]);
        acc[j] = __builtin_amdgcn_mfma_f32_16x16x32_bf16(a[ks], b, acc[j], 0, 0, 0);
      }

    if (tile) __syncthreads();   // prev tile's column loops done -> hatB free
#pragma unroll
    for (int j = 0; j < 8; ++j)
#pragma unroll
      for (int r = 0; r < 4; ++r)
        hatB[w * 16 + quad * 4 + r][j * 16 + l16] = f2bf(acc[j][r]);
    __syncthreads();

    // ---- row-major read phase (rotated sub-segments) ----
    {
      const int r = er, seg = t & 3;
      const size_t row = row0 + r;
      const int si = sI[tile], di = dI[tile];
      if (seg == 0) dstL[r] = di;
      const unsigned short* g1p = &G1[(size_t)si * 128];
      const unsigned short* g2p = &G2[(size_t)di * 128];
#pragma unroll
      for (int q2 = 0; q2 < 4; ++q2) {
        const int cc = seg * 32 + (((q2 + seg) & 3) << 3);
        uint4 mm = *reinterpret_cast<const uint4*>(&hatB[r][cc]);
        float4 b0 = *reinterpret_cast<const float4*>(&bias[cc]);
        float4 b1 = *reinterpret_cast<const float4*>(&bias[cc + 4]);
        uint4 g1 = *reinterpret_cast<const uint4*>(&g1p[cc]);
        uint4 g2 = *reinterpret_cast<const uint4*>(&g2p[cc]);
        unsigned int mw[4] = {mm.x, mm.y, mm.z, mm.w};
        unsigned int g1w[4] = {g1.x, g1.y, g1.z, g1.w};
        unsigned int g2w[4] = {g2.x, g2.y, g2.z, g2.w};
        float bv[8] = {b0.x, b0.y, b0.z, b0.w, b1.x, b1.y, b1.z, b1.w};
        unsigned int pk[4];
#pragma unroll
        for (int i = 0; i < 4; ++i) {
          float vlo = bf2f((unsigned short)(mw[i] & 0xffffu)) + bv[2 * i]
                    + bf2f((unsigned short)(g1w[i] & 0xffffu))
                    + bf2f((unsigned short)(g2w[i] & 0xffffu));
          float vhi = bf2f((unsigned short)(mw[i] >> 16)) + bv[2 * i + 1]
                    + bf2f((unsigned short)(g1w[i] >> 16))
                    + bf2f((unsigned short)(g2w[i] >> 16));
          pk[i] = (unsigned int)f2bf(vlo) | ((unsigned int)f2bf(vhi) << 16);
        }
        uint4 st; st.x = pk[0]; st.y = pk[1]; st.z = pk[2]; st.w = pk[3];
        *reinterpret_cast<uint4*>(&hat[row * 128 + cc]) = st;
        *reinterpret_cast<uint4*>(&hatB[r][cc]) = st;   // rounded write-back
      }
    }
    __syncthreads();

    // ---- unified column loop: 256 threads, 32 rows each ----
    {
      const int c = t & 127;
      const int r0c = (t >> 7) * 32;
      float s = 0.f, q = 0.f;
      float run = 0.f;
      int prev = dstL[r0c];
      for (int r = r0c; r < r0c + 32; ++r) {
        float v = bf2f(hatB[r][c]);
        if (WITH_STATS) { s += v; q += v * v; }
        int d = dstL[r];               // wave-uniform
        float sg = sigmoidf_(v);
        if (d != prev) {               // wave-uniform branch
          atomicAdd(&ssum[(size_t)prev * 128 + c], run);
          run = 0.f; prev = d;
        }
        run += sg;
      }
      atomicAdd(&ssum[(size_t)prev * 128 + c], run);
      if (WITH_STATS) { stat_s += s; stat_q += q; }
    }
  }

  if (WITH_STATS) {
    const int c = t & 127;
    atomicAdd(&stats[c], stat_s);
    atomicAdd(&stats[128 + c], stat_q);
  }
}

// ---------------------------------------------------------------------------
// Fused node GEMMs: B1,B2 (bf16 out); A1,A2,C1,C2 (fp32 out).
// Block 256 = 4 waves, 64 rows; hp tile staged in LDS once; W direct from L2.
// ---------------------------------------------------------------------------
__global__ __launch_bounds__(256)
void ngemm6(const unsigned short* __restrict__ hp,
            const unsigned short* __restrict__ WtL,
            const float* __restrict__ B1b, const float* __restrict__ B2b,
            const float* __restrict__ A1b, const float* __restrict__ A2b,
            const float* __restrict__ C1b, const float* __restrict__ C2b,
            unsigned short* __restrict__ B1h, unsigned short* __restrict__ B2h,
            float* __restrict__ A1hp, float* __restrict__ A2hp,
            float* __restrict__ C1p, float* __restrict__ C2p)
{
  __shared__ unsigned short As[64][264];

  const int t    = threadIdx.x;
  const int w    = t >> 6;
  const int lane = t & 63;
  const int quad = lane >> 4;
  const int l16  = lane & 15;
  const size_t row0 = (size_t)blockIdx.x * 64;

#pragma unroll
  for (int i = 0; i < 8; ++i) {
    int flat = i * 256 + t;
    int r = flat >> 5, g = flat & 31;
    *reinterpret_cast<uint4*>(&As[r][g * 8]) =
        *reinterpret_cast<const uint4*>(&hp[(row0 + r) * 256 + g * 8]);
  }
  __syncthreads();

  const unsigned short* Wm[6] = {WtL, WtL + 16384, WtL + 49152, WtL + 81920,
                                 WtL + 114688, WtL + 131072};
  const int Kk[6]   = {128, 128, 256, 256, 128, 128};
  const int koff[6] = {0, 0, 0, 0, 128, 128};
  const float* bs[6] = {B1b, B2b, A1b, A2b, C1b, C2b};
  float* outf[6] = {nullptr, nullptr, A1hp, A2hp, C1p, C2p};
  unsigned short* outb[2] = {B1h, B2h};

  for (int m = 0; m < 6; ++m) {
    const unsigned short* W = Wm[m];
    const int K = Kk[m], ko = koff[m];
    float4v acc[8];
#pragma unroll
    for (int j = 0; j < 8; ++j) acc[j] = (float4v){0.f, 0.f, 0.f, 0.f};
    for (int ks = 0; ks < K / 32; ++ks) {
      short8 aa = *reinterpret_cast<const short8*>(&As[w * 16 + l16][ko + ks * 32 + quad * 8]);
#pragma unroll
      for (int j = 0; j < 8; ++j) {
        short8 b = *reinterpret_cast<const short8*>(&W[(size_t)(j * 16 + l16) * K + ks * 32 + quad * 8]);
        acc[j] = __builtin_amdgcn_mfma_f32_16x16x32_bf16(aa, b, acc[j], 0, 0, 0);
      }
    }
    const float* bb = bs[m];
    if (m < 2) {
      unsigned short* o = outb[m];
#pragma unroll
      for (int j = 0; j < 8; ++j) {
        int col = j * 16 + l16;
        float bc = bb[col];
#pragma unroll
        for (int r = 0; r < 4; ++r) {
          size_t orow = row0 + w * 16 + quad * 4 + r;
          o[orow * 128 + col] = f2bf(acc[j][r] + bc);
        }
      }
    } else {
      float* o = outf[m];
#pragma unroll
      for (int j = 0; j < 8; ++j) {
        int col = j * 16 + l16;
        float bc = bb[col];
#pragma unroll
        for (int r = 0; r < 4; ++r) {
          size_t orow = row0 + w * 16 + quad * 4 + r;
          o[orow * 128 + col] = acc[j][r] + bc;
        }
      }
    }
  }
}

// ---------------------------------------------------------------------------
// Weight prep -> bf16 transposed Wt[n][k]. Per layer (ushort offsets):
// B1@0 B2@16384 B3@32768 A1@49152 A2@81920 C1@114688 C2@131072; stride 147456.
// ---------------------------------------------------------------------------
__global__ void prep_weights(const float* __restrict__ B1, const float* __restrict__ B2,
                             const float* __restrict__ B3, const float* __restrict__ A1,
                             const float* __restrict__ A2, const float* __restrict__ C1,
                             const float* __restrict__ C2, unsigned short* __restrict__ Wt)
{
  int idx = blockIdx.x * 256 + threadIdx.x;
  if (idx >= 4 * 147456) return;
  int layer = idx / 147456;
  int o = idx - layer * 147456;
  const float* src; int K, local;
  if (o < 16384)       { src = B1 + layer * 16384; local = o;          K = 128; }
  else if (o < 32768)  { src = B2 + layer * 16384; local = o - 16384;  K = 128; }
  else if (o < 49152)  { src = B3 + layer * 16384; local = o - 32768;  K = 128; }
  else if (o < 81920)  { src = A1 + layer * 32768; local = o - 49152;  K = 256; }
  else if (o < 114688) { src = A2 + layer * 32768; local = o - 81920;  K = 256; }
  else if (o < 131072) { src = C1 + layer * 16384; local = o - 114688; K = 128; }
  else                 { src = C2 + layer * 16384; local = o - 131072; K = 128; }
  int n = local / K, k = local - n * K;
  Wt[idx] = f2bf(src[k * 128 + n]);
}

// hp_bf[n][0:128]=bf16(h), [128:256]=bf16(pc)  (initial build only)
__global__ void convert_hp(const float* __restrict__ h, const float* __restrict__ pc,
                           unsigned short* __restrict__ hp)
{
  int t = blockIdx.x * 256 + threadIdx.x;
  if (t >= N_NODES * 64) return;
  int n = t >> 6, part = t & 63;
  float4 v = (part < 32) ? reinterpret_cast<const float4*>(h)[n * 32 + part]
                         : reinterpret_cast<const float4*>(pc)[n * 32 + (part - 32)];
  ushort4 o;
  o.x = f2bf(v.x); o.y = f2bf(v.y); o.z = f2bf(v.z); o.w = f2bf(v.w);
  reinterpret_cast<ushort4*>(hp)[n * 64 + part] = o;
}

// ---------------------------------------------------------------------------
__global__ void embed_nodes_k(const int* __restrict__ idx, const float* __restrict__ table,
                              float* __restrict__ out, int M)
{
  int t = blockIdx.x * 256 + threadIdx.x;
  if (t < M * 32) {
    int r = t >> 5, c = t & 31;
    reinterpret_cast<float4*>(out)[t] =
        reinterpret_cast<const float4*>(table)[idx[r] * 32 + c];
  }
}

__global__ void embed_edges_bf(const int* __restrict__ bonds, const int* __restrict__ eidx,
                               const float* __restrict__ table,
                               unsigned short* __restrict__ out, int M)
{
  int t = blockIdx.x * 256 + threadIdx.x;
  if (t < M * 32) {
    int r = t >> 5, c = t & 31;
    float4 v = reinterpret_cast<const float4*>(table)[bonds[eidx[r]] * 32 + c];
    ushort4 o;
    o.x = f2bf(v.x); o.y = f2bf(v.y); o.z = f2bf(v.z); o.w = f2bf(v.w);
    reinterpret_cast<ushort4*>(out)[t] = o;
  }
}

// ---------------------------------------------------------------------------
// CSR build over dst + edge permutation (per-graph parallel scan).
// ---------------------------------------------------------------------------
__global__ void hist_k(const int* __restrict__ dstI, int* __restrict__ deg, int E)
{
  int e = blockIdx.x * 256 + threadIdx.x;
  if (e < E) atomicAdd(&deg[dstI[e]], 1);
}

__global__ __launch_bounds__(640)
void scan64_k(const int* __restrict__ deg, int* __restrict__ row_start,
              int* __restrict__ cursor)
{
  __shared__ int buf[640];
  const int g = blockIdx.x;
  const int t = threadIdx.x;
  const int n = g * NPG + t;
  int v = deg[n];
  buf[t] = v;
  __syncthreads();
#pragma unroll
  for (int off = 1; off < 640; off <<= 1) {
    int add = (t >= off) ? buf[t - off] : 0;
    __syncthreads();
    buf[t] += add;
    __syncthreads();
  }
  int excl = g * EPG + buf[t] - v;
  row_start[n] = excl;
  cursor[n] = excl;
  if (g == 0 && t == 0) row_start[N_NODES] = N_EDGES;
}

__global__ void fill_k(const int* __restrict__ dstI, int* __restrict__ cursor,
                       int* __restrict__ eidx, int E)
{
  int e = blockIdx.x * 256 + threadIdx.x;
  if (e < E) {
    int p = atomicAdd(&cursor[dstI[e]], 1);
    eidx[p] = e;
  }
}

__global__ void permute_sd(const int* __restrict__ eidx, const int* __restrict__ srcI,
                           const int* __restrict__ dstI, int* __restrict__ srcp,
                           int* __restrict__ dstp, int E)
{
  int e = blockIdx.x * 256 + threadIdx.x;
  if (e < E) {
    int o = eidx[e];
    srcp[e] = srcI[o];
    dstp[e] = dstI[o];
  }
}

// ---------------------------------------------------------------------------
// Single-pass gate aggregation (ssum precomputed in egemm) + fused ef update
// + hp pc-half write. One wave per node, 2 cols/lane. fp32 A2hp/C2p tables
// (bf16 tables measured slower twice: latency-bound gather, r8/r12).
// Re-zeros ssum after use (replaces per-layer memset).
// ---------------------------------------------------------------------------
template <int EF_UPD>
__global__ __launch_bounds__(256)
void gate_agg5(const unsigned short* __restrict__ hat, const int* __restrict__ row_start,
               const int* __restrict__ srcp, float* __restrict__ ssum,
               const float* __restrict__ A1hp, const float* __restrict__ A2hp,
               const float* __restrict__ C1p, const float* __restrict__ C2p,
               float* __restrict__ hraw, float* __restrict__ pc,
               unsigned short* __restrict__ ef, const float* __restrict__ ss_e,
               unsigned short* __restrict__ hp)
{
  int t = threadIdx.x;
  int node = blockIdx.x * 4 + (t >> 6);
  int lane = t & 63;
  int c = lane * 2;
  int beg = row_start[node], end = row_start[node + 1];

  float2 sv = *reinterpret_cast<const float2*>(&ssum[(size_t)node * 128 + c]);
  float2 zz; zz.x = 0.f; zz.y = 0.f;
  *reinterpret_cast<float2*>(&ssum[(size_t)node * 128 + c]) = zz;  // re-zero for next layer
  float inv0 = 1.f / (sv.x + GATE_EPS);
  float inv1 = 1.f / (sv.y + GATE_EPS);

  float2 eA, eB;
  if (EF_UPD) {
    eA = *reinterpret_cast<const float2*>(&ss_e[c]);
    eB = *reinterpret_cast<const float2*>(&ss_e[128 + c]);
  }

  float ha0 = 0.f, ha1 = 0.f, pa0 = 0.f, pa1 = 0.f;
  for (int e = beg; e < end; ++e) {
    int s = srcp[e];
    ushort2 hv = *reinterpret_cast<const ushort2*>(&hat[(size_t)e * 128 + c]);
    float hx = bf2f(hv.x), hy = bf2f(hv.y);
    float w0 = sigmoidf_(hx) * inv0;
    float w1 = sigmoidf_(hy) * inv1;
    float2 a2 = *reinterpret_cast<const float2*>(&A2hp[(size_t)s * 128 + c]);
    float2 c2 = *reinterpret_cast<const float2*>(&C2p[(size_t)s * 128 + c]);
    ha0 += w0 * a2.x; ha1 += w1 * a2.y;
    pa0 += w0 * c2.x; pa1 += w1 * c2.y;
    if (EF_UPD) {
      ushort2 ev = *reinterpret_cast<ushort2*>(&ef[(size_t)e * 128 + c]);
      float ex = bf2f(ev.x) + fmaxf(hx * eA.x + eB.x, 0.f);
      float ey = bf2f(ev.y) + fmaxf(hy * eA.y + eB.y, 0.f);
      ushort2 eo; eo.x = f2bf(ex); eo.y = f2bf(ey);
      *reinterpret_cast<ushort2*>(&ef[(size_t)e * 128 + c]) = eo;
    }
  }
  size_t ix = (size_t)node * 128 + c;
  float2 a1 = *reinterpret_cast<const float2*>(&A1hp[ix]);
  float2 c1 = *reinterpret_cast<const float2*>(&C1p[ix]);
  float2 hv; hv.x = a1.x + ha0; hv.y = a1.y + ha1;
  *reinterpret_cast<float2*>(&hraw[ix]) = hv;
  float2 pv = *reinterpret_cast<float2*>(&pc[ix]);
  pv.x += tanhf(c1.x + pa0);
  pv.y += tanhf(c1.y + pa1);
  *reinterpret_cast<float2*>(&pc[ix]) = pv;
  ushort2 ph; ph.x = f2bf(pv.x); ph.y = f2bf(pv.y);
  *reinterpret_cast<ushort2*>(&hp[(size_t)node * 256 + 128 + c]) = ph;
}

// ---------------------------------------------------------------------------
__global__ __launch_bounds__(128)
void col_stats(const float* __restrict__ x, float* __restrict__ stats, int rowsPerBlock)
{
  int d = threadIdx.x;
  size_t r0 = (size_t)blockIdx.x * rowsPerBlock;
  float s = 0.f, q = 0.f;
  for (int i = 0; i < rowsPerBlock; ++i) {
    float v = x[(r0 + i) * 128 + d];
    s += v; q += v * v;
  }
  atomicAdd(&stats[d], s);
  atomicAdd(&stats[128 + d], q);
}

__global__ void bn_finalize(const float* __restrict__ stats, const float* __restrict__ g,
                            const float* __restrict__ b, float invM, float* __restrict__ ss)
{
  int c = threadIdx.x;
  float m = stats[c] * invM;
  float v = stats[128 + c] * invM - m * m;
  float A = rsqrtf(v + BN_EPS) * g[c];
  ss[c] = A;
  ss[128 + c] = b[c] - m * A;
}

// h += relu(hraw*A+B); also writes bf16(h) into hp cols 0..127
__global__ void apply_h(float* __restrict__ dest, const float* __restrict__ xraw,
                        const float* __restrict__ ss, unsigned short* __restrict__ hp,
                        int total4)
{
  int t = blockIdx.x * 256 + threadIdx.x;
  if (t >= total4) return;
  int c4 = t & 31, n = t >> 5;
  float4 x = reinterpret_cast<const float4*>(xraw)[t];
  float4 A = reinterpret_cast<const float4*>(ss)[c4];
  float4 B = reinterpret_cast<const float4*>(ss + 128)[c4];
  float4 dv = reinterpret_cast<float4*>(dest)[t];
  dv.x += fmaxf(x.x * A.x + B.x, 0.f);
  dv.y += fmaxf(x.y * A.y + B.y, 0.f);
  dv.z += fmaxf(x.z * A.z + B.z, 0.f);
  dv.w += fmaxf(x.w * A.w + B.w, 0.f);
  reinterpret_cast<float4*>(dest)[t] = dv;
  ushort4 o;
  o.x = f2bf(dv.x); o.y = f2bf(dv.y); o.z = f2bf(dv.z); o.w = f2bf(dv.w);
  *reinterpret_cast<ushort4*>(&hp[(size_t)n * 256 + c4 * 4]) = o;
}

// ---------------------------------------------------------------------------
// fp32 GEMM kept for pc-embedding (K=16) and Whp graph-mean (MODE 2)
// ---------------------------------------------------------------------------
template <int MODE>
__global__ __launch_bounds__(256)
void gemm_k(const float* __restrict__ Xa, int Ka,
            const float* __restrict__ Xb, int Kb,
            const float* __restrict__ W,
            const float* __restrict__ bias,
            float* __restrict__ out,
            float* __restrict__ hg, float inv_nodes, int npg)
{
  __shared__ float Xs[16][68];
  __shared__ float Ws[16][128];
  __shared__ float red[8][128];

  const int t  = threadIdx.x;
  const int ty = t >> 5;
  const int tx = t & 31;
  const int row0 = blockIdx.x * 64;
  const int K = Ka + Kb;

  float acc[8][4];
#pragma unroll
  for (int i = 0; i < 8; ++i)
#pragma unroll
    for (int j = 0; j < 4; ++j) acc[i][j] = 0.f;

  const int xr = t >> 2;
  const int xk = (t & 3) << 2;
  const int wr = t >> 5;
  const int wc = tx << 2;

  for (int kk = 0; kk < K; kk += 16) {
    const float* xbase; int ldk, kloc;
    if (kk < Ka) { xbase = Xa; ldk = Ka; kloc = kk; }
    else         { xbase = Xb; ldk = Kb; kloc = kk - Ka; }
    float4 xv = *reinterpret_cast<const float4*>(
        &xbase[(size_t)(row0 + xr) * ldk + kloc + xk]);
    Xs[xk + 0][xr] = xv.x; Xs[xk + 1][xr] = xv.y;
    Xs[xk + 2][xr] = xv.z; Xs[xk + 3][xr] = xv.w;

    float4 wv0 = *reinterpret_cast<const float4*>(&W[(size_t)(kk + wr) * 128 + wc]);
    float4 wv1 = *reinterpret_cast<const float4*>(&W[(size_t)(kk + wr + 8) * 128 + wc]);
    *reinterpret_cast<float4*>(&Ws[wr][wc])     = wv0;
    *reinterpret_cast<float4*>(&Ws[wr + 8][wc]) = wv1;
    __syncthreads();

#pragma unroll
    for (int k = 0; k < 16; ++k) {
      float4 b4 = *reinterpret_cast<const float4*>(&Ws[k][wc]);
      float4 a0 = *reinterpret_cast<const float4*>(&Xs[k][ty << 3]);
      float4 a1 = *reinterpret_cast<const float4*>(&Xs[k][(ty << 3) + 4]);
      float a[8] = {a0.x, a0.y, a0.z, a0.w, a1.x, a1.y, a1.z, a1.w};
      float b[4] = {b4.x, b4.y, b4.z, b4.w};
#pragma unroll
      for (int i = 0; i < 8; ++i) {
        acc[i][0] += a[i] * b[0];
        acc[i][1] += a[i] * b[1];
        acc[i][2] += a[i] * b[2];
        acc[i][3] += a[i] * b[3];
      }
    }
    __syncthreads();
  }

  float4 bb = *reinterpret_cast<const float4*>(&bias[wc]);
  float bv[4] = {bb.x, bb.y, bb.z, bb.w};

  if (MODE == 0) {
#pragma unroll
    for (int i = 0; i < 8; ++i) {
      int r = row0 + (ty << 3) + i;
      float4 ov;
      ov.x = acc[i][0] + bv[0]; ov.y = acc[i][1] + bv[1];
      ov.z = acc[i][2] + bv[2]; ov.w = acc[i][3] + bv[3];
      *reinterpret_cast<float4*>(&out[(size_t)r * 128 + wc]) = ov;
    }
  } else {
    float csum[4] = {0, 0, 0, 0};
#pragma unroll
    for (int i = 0; i < 8; ++i) {
      csum[0] += acc[i][0]; csum[1] += acc[i][1];
      csum[2] += acc[i][2]; csum[3] += acc[i][3];
    }
#pragma unroll
    for (int j = 0; j < 4; ++j) red[ty][wc + j] = csum[j];
    __syncthreads();
    if (ty == 0) {
      int g = row0 / npg;
#pragma unroll
      for (int j = 0; j < 4; ++j) {
        float s = 0;
#pragma unroll
        for (int q = 0; q < 8; ++q) s += red[q][wc + j];
        atomicAdd(&hg[(size_t)g * 128 + wc + j], (s + 64.f * bv[j]) * inv_nodes);
      }
    }
  }
}

// ---------------------------------------------------------------------------
__global__ __launch_bounds__(256)
void po_gemm(const float* __restrict__ pc, const float* __restrict__ w,
             const float* __restrict__ b, float* __restrict__ po)
{
  __shared__ float pcs[16][128];
  __shared__ float wl[128][16];
  int t = threadIdx.x;
  int n0 = blockIdx.x * 16;
  for (int i = t; i < 512; i += 256) {
    int r = i >> 5, c = (i & 31) << 2;
    *reinterpret_cast<float4*>(&pcs[r][c]) =
        *reinterpret_cast<const float4*>(&pc[(size_t)(n0 + r) * 128 + c]);
  }
  for (int i = t; i < 512; i += 256) {
    int r = i >> 2, c = (i & 3) << 2;
    *reinterpret_cast<float4*>(&wl[r][c]) =
        *reinterpret_cast<const float4*>(&w[r * 16 + c]);
  }
  __syncthreads();
  int i = t >> 4, j = t & 15;
  float acc = b[j];
  for (int k = 0; k < 128; ++k) acc += pcs[i][k] * wl[k][j];
  po[(size_t)(n0 + i) * 16 + j] = acc;
}

__global__ __launch_bounds__(256)
void pe_norm(float* __restrict__ po)
{
  int g = blockIdx.x;
  int t = threadIdx.x;
  int j = t & 15, grp = t >> 4;
  __shared__ float red[16][16];
  __shared__ float mean_s[16];
  __shared__ float nrm_s[16];
  size_t bse = (size_t)g * NPG * 16;
  float s = 0.f;
  for (int i = grp; i < NPG; i += 16) s += po[bse + i * 16 + j];
  red[grp][j] = s;
  __syncthreads();
  if (grp == 0) {
    float m = 0.f;
    for (int q = 0; q < 16; ++q) m += red[q][j];
    mean_s[j] = m / NPG;
  }
  __syncthreads();
  float m = mean_s[j];
  float q2 = 0.f;
  for (int i = grp; i < NPG; i += 16) {
    float c = po[bse + i * 16 + j] - m;
    q2 += c * c;
  }
  red[grp][j] = q2;
  __syncthreads();
  if (grp == 0) {
    float v = 0.f;
    for (int q = 0; q < 16; ++q) v += red[q][j];
    nrm_s[j] = sqrtf(v);
  }
  __syncthreads();
  float inv = 1.f / nrm_s[j];
  for (int i = grp; i < NPG; i += 16) {
    size_t ix = bse + i * 16 + j;
    po[ix] = (po[ix] - m) * inv;
  }
}

__global__ __launch_bounds__(256)
void mlp_head(const float* __restrict__ hg,
              const float* __restrict__ w0, const float* __restrict__ b0,
              const float* __restrict__ w1, const float* __restrict__ b1,
              const float* __restrict__ w2, const float* __restrict__ b2,
              float* __restrict__ out)
{
  __shared__ float hs[64 * 128];
  __shared__ float y0[64 * 64];
  __shared__ float y1[64 * 32];
  int t = threadIdx.x;
  for (int i = t; i < 64 * 128 / 4; i += 256)
    reinterpret_cast<float4*>(hs)[i] = reinterpret_cast<const float4*>(hg)[i];
  __syncthreads();
  for (int o = t; o < 64 * 64; o += 256) {
    int i = o >> 6, j = o & 63;
    float a = b0[j];
    for (int k = 0; k < 128; ++k) a += hs[i * 128 + k] * w0[k * 64 + j];
    y0[o] = fmaxf(a, 0.f);
  }
  __syncthreads();
  for (int o = t; o < 64 * 32; o += 256) {
    int i = o >> 5, j = o & 31;
    float a = b1[j];
    for (int k = 0; k < 64; ++k) a += y0[i * 64 + k] * w1[k * 32 + j];
    y1[o] = fmaxf(a, 0.f);
  }
  __syncthreads();
  if (t < 64) {
    float a = b2[0];
    for (int k = 0; k < 32; ++k) a += y1[t * 32 + k] * w2[k];
    out[t] = a;
  }
}

__global__ void fill_sentinel(float* out, int n, float v)
{
  int t = blockIdx.x * 256 + threadIdx.x;
  if (t < n) out[t] = v;
}

// ---------------------------------------------------------------------------
extern "C" void kernel_launch(void* const* d_in, const int* in_sizes, int n_in,
                              void* d_out, int out_size, void* d_ws, size_t ws_size,
                              hipStream_t stream)
{
  const int*   h_atoms = (const int*)d_in[0];
  const int*   e_bonds = (const int*)d_in[1];
  const int*   srcI    = (const int*)d_in[2];
  const int*   dstI    = (const int*)d_in[3];
  const float* p_in    = (const float*)d_in[5];
  const float* W_emb_h = (const float*)d_in[6];
  const float* W_emb_p = (const float*)d_in[7];
  const float* b_emb_p = (const float*)d_in[8];
  const float* W_emb_e = (const float*)d_in[9];
  const float* A1_w = (const float*)d_in[10];
  const float* A1_b = (const float*)d_in[11];
  const float* A2_w = (const float*)d_in[12];
  const float* A2_b = (const float*)d_in[13];
  const float* B1_w = (const float*)d_in[14];
  const float* B1_b = (const float*)d_in[15];
  const float* B2_w = (const float*)d_in[16];
  const float* B2_b = (const float*)d_in[17];
  const float* B3_w = (const float*)d_in[18];
  const float* B3_b = (const float*)d_in[19];
  const float* C1_w = (const float*)d_in[20];
  const float* C1_b = (const float*)d_in[21];
  const float* C2_w = (const float*)d_in[22];
  const float* C2_b = (const float*)d_in[23];
  const float* bn_h_g = (const float*)d_in[24];
  const float* bn_h_b = (const float*)d_in[25];
  const float* bn_e_g = (const float*)d_in[26];
  const float* bn_e_b = (const float*)d_in[27];
  const float* p_out_w = (const float*)d_in[28];
  const float* p_out_b = (const float*)d_in[29];
  const float* Whp_w   = (const float*)d_in[30];
  const float* Whp_b   = (const float*)d_in[31];
  const float* mlp_w0  = (const float*)d_in[32];
  const float* mlp_b0  = (const float*)d_in[33];
  const float* mlp_w1  = (const float*)d_in[34];
  const float* mlp_b1  = (const float*)d_in[35];
  const float* mlp_w2  = (const float*)d_in[36];
  const float* mlp_b2  = (const float*)d_in[37];

  static void* pool_ptr = nullptr;
  if (!pool_ptr) {
    if (hipGetSymbolAddress(&pool_ptr, HIP_SYMBOL(g_pool)) != hipSuccess || !pool_ptr) {
      fill_sentinel<<<dim3(1), dim3(256), 0, stream>>>((float*)d_out, out_size, 12345.0f);
      return;
    }
  }

  float* fbase = (float*)pool_ptr;
  size_t fo = 0;
  auto carvef = [&](size_t nf) { float* r = fbase + fo; fo += nf; return r; };
  float* h    = carvef((size_t)N_NODES * DH);
  float* pc   = carvef((size_t)N_NODES * DH);
  float* A1hp = carvef((size_t)N_NODES * DH);
  float* A2hp = carvef((size_t)N_NODES * DH);
  float* C1p  = carvef((size_t)N_NODES * DH);
  float* C2p  = carvef((size_t)N_NODES * DH);
  float* hraw = carvef((size_t)N_NODES * DH);
  float* ssum = carvef((size_t)N_NODES * DH);
  float* po   = carvef((size_t)N_NODES * 16);
  float* hg   = carvef(NGRAPH * 128);
  float* estats = carvef(256);
  float* hstats = carvef(256);
  float* ss_e   = carvef(256);
  float* ss_h   = carvef(256);

  unsigned short* ubase = (unsigned short*)(fbase + fo);
  unsigned short* ef_bf  = ubase;
  unsigned short* hat_bf = ef_bf + (size_t)N_EDGES * DH;
  unsigned short* hp_bf  = hat_bf + (size_t)N_EDGES * DH;
  unsigned short* b1_bf  = hp_bf + (size_t)N_NODES * 256;
  unsigned short* b2_bf  = b1_bf + (size_t)N_NODES * DH;
  unsigned short* Wt_bf  = b2_bf + (size_t)N_NODES * DH;
  int* ibase = (int*)(Wt_bf + 4 * 147456);
  int* deg       = ibase;
  int* row_start = deg + N_NODES;
  int* cursor    = row_start + (N_NODES + 3);
  int* eidx      = cursor + N_NODES;
  int* srcp      = eidx + N_EDGES;
  int* dstp      = srcp + N_EDGES;

  dim3 b256(256);

  // --- weight prep ---
  prep_weights<<<dim3((4 * 147456 + 255) / 256), b256, 0, stream>>>(
      B1_w, B2_w, B3_w, A1_w, A2_w, C1_w, C2_w, Wt_bf);

  // --- CSR over dst + permutation (per-graph parallel scan) ---
  hipMemsetAsync(deg, 0, N_NODES * sizeof(int), stream);
  hipMemsetAsync(ssum, 0, (size_t)N_NODES * DH * sizeof(float), stream);
  hist_k<<<dim3((N_EDGES + 255) / 256), b256, 0, stream>>>(dstI, deg, N_EDGES);
  scan64_k<<<dim3(NGRAPH), dim3(640), 0, stream>>>(deg, row_start, cursor);
  fill_k<<<dim3((N_EDGES + 255) / 256), b256, 0, stream>>>(dstI, cursor, eidx, N_EDGES);
  permute_sd<<<dim3((N_EDGES + 255) / 256), b256, 0, stream>>>(eidx, srcI, dstI, srcp, dstp, N_EDGES);

  // --- embeddings (edges in CSR order) ---
  embed_nodes_k<<<dim3((N_NODES * 32 + 255) / 256), b256, 0, stream>>>(h_atoms, W_emb_h, h, N_NODES);
  embed_edges_bf<<<dim3((N_EDGES * 32 + 255) / 256), b256, 0, stream>>>(
      e_bonds, eidx, W_emb_e, ef_bf, N_EDGES);
  gemm_k<0><<<dim3(N_NODES / 64), b256, 0, stream>>>(
      p_in, 16, nullptr, 0, W_emb_p, b_emb_p, pc, nullptr, 0.f, NPG);
  convert_hp<<<dim3(N_NODES * 64 / 256), b256, 0, stream>>>(h, pc, hp_bf);

  const dim3 gNode64(N_NODES / 64), gEdge(N_EDGES / (64 * ETPB));

  // --- layers ---
  for (int l = 0; l < NLAYERS; ++l) {
    const unsigned short* WtL = Wt_bf + (size_t)l * 147456;
    const unsigned short* WtB3 = WtL + 32768;
    const bool last = (l == NLAYERS - 1);

    ngemm6<<<gNode64, b256, 0, stream>>>(hp_bf, WtL,
        B1_b + l * 128, B2_b + l * 128, A1_b + l * 128, A2_b + l * 128,
        C1_b + l * 128, C2_b + l * 128, b1_bf, b2_bf, A1hp, A2hp, C1p, C2p);

    if (!last) {
      hipMemsetAsync(estats, 0, 256 * sizeof(float), stream);
      egemm<1><<<gEdge, b256, 0, stream>>>(ef_bf, WtB3, B3_b + l * 128, hat_bf,
          srcp, dstp, b1_bf, b2_bf, estats, ssum);
      bn_finalize<<<dim3(1), dim3(128), 0, stream>>>(
          estats, bn_e_g + l * 128, bn_e_b + l * 128, 1.f / N_EDGES, ss_e);
      gate_agg5<1><<<dim3(N_NODES / 4), b256, 0, stream>>>(
          hat_bf, row_start, srcp, ssum, A1hp, A2hp, C1p, C2p, hraw, pc,
          ef_bf, ss_e, hp_bf);
    } else {
      egemm<0><<<gEdge, b256, 0, stream>>>(ef_bf, WtB3, B3_b + l * 128, hat_bf,
          srcp, dstp, b1_bf, b2_bf, nullptr, ssum);
      gate_agg5<0><<<dim3(N_NODES / 4), b256, 0, stream>>>(
          hat_bf, row_start, srcp, ssum, A1hp, A2hp, C1p, C2p, hraw, pc,
          nullptr, nullptr, hp_bf);
    }

    hipMemsetAsync(hstats, 0, 256 * sizeof(float), stream);
    col_stats<<<dim3(128), dim3(128), 0, stream>>>(hraw, hstats, N_NODES / 128);
    bn_finalize<<<dim3(1), dim3(128), 0, stream>>>(
        hstats, bn_h_g + l * 128, bn_h_b + l * 128, 1.f / N_NODES, ss_h);

    apply_h<<<dim3(N_NODES * 32 / 256), b256, 0, stream>>>(
        h, hraw, ss_h, hp_bf, N_NODES * 32);
  }

  // --- PE output head ---
  po_gemm<<<dim3(N_NODES / 16), b256, 0, stream>>>(pc, p_out_w, p_out_b, po);
  pe_norm<<<dim3(NGRAPH), b256, 0, stream>>>(po);

  hipMemsetAsync(hg, 0, NGRAPH * 128 * sizeof(float), stream);
  gemm_k<2><<<dim3(N_NODES / 64), b256, 0, stream>>>(
      h, 128, po, 16, Whp_w, Whp_b, nullptr, hg, 1.f / NPG, NPG);

  mlp_head<<<dim3(1), b256, 0, stream>>>(
      hg, mlp_w0, mlp_b0, mlp_w1, mlp_b1, mlp_w2, mlp_b2, (float*)d_out);
}

// Round 15
// 2798.482 us; speedup vs baseline: 1.1196x; 1.1196x over previous
//
#include <hip/hip_runtime.h>
#include <math.h>

#define N_NODES 40960
#define N_EDGES 655360
#define NPG     640
#define NGRAPH  64
#define EPG     10240   // edges per graph (E / NGRAPH, exact)
#define DH      128
#define NLAYERS 4
#define GATE_EPS 1e-6f
#define BN_EPS   1e-5f
#define ETPB    8     // egemm row-tiles (64 rows each) per block

// Static device scratch pool (module-load allocated; graph-capture safe).
#define POOL_BYTES 580000000ull
__device__ __attribute__((aligned(256))) unsigned char g_pool[POOL_BYTES];

using short8  = __attribute__((ext_vector_type(8))) short;
using float4v = __attribute__((ext_vector_type(4))) float;

static __device__ __forceinline__ float sigmoidf_(float x) {
  return 1.f / (1.f + __expf(-x));
}
static __device__ __forceinline__ unsigned short f2bf(float f) {
  unsigned int u = __float_as_uint(f);
  unsigned int r = 0x7FFFu + ((u >> 16) & 1u);
  return (unsigned short)((u + r) >> 16);
}
static __device__ __forceinline__ float bf2f(unsigned short h) {
  return __uint_as_float(((unsigned int)h) << 16);
}

// ---------------------------------------------------------------------------
// Edge-gate GEMM, CSR-ordered edges, ETPB 64-row tiles per block.
// hat[e,:] = bf16(ef@B3 + b3 + G1[src] + G2[dst])   (G1,G2 in bf16)
// W staged in LDS (r14 showed L2-direct W -> VGPR 140, occupancy 11%: worse).
// hatB bf16 -> LDS 52.5KB -> 3 blocks/CU. Unified column loop (256 thr).
// ---------------------------------------------------------------------------
template <int WITH_STATS>
__global__ __launch_bounds__(256)
void egemm(const unsigned short* __restrict__ ef,
           const unsigned short* __restrict__ Wt,
           const float* __restrict__ bias,
           unsigned short* __restrict__ hat,
           const int* __restrict__ srcp, const int* __restrict__ dstp,
           const unsigned short* __restrict__ G1, const unsigned short* __restrict__ G2,
           float* __restrict__ stats, float* __restrict__ ssum)
{
  __shared__ unsigned short Ws[128][136];
  __shared__ unsigned short hatB[64][136];
  __shared__ int dstL[64];

  const int t    = threadIdx.x;
  const int w    = t >> 6;
  const int lane = t & 63;
  const int quad = lane >> 4;
  const int l16  = lane & 15;
  const size_t base = (size_t)blockIdx.x * (64 * ETPB);
  const int er = t >> 2;                       // epilogue row 0..63

  // prefetch src/dst for this thread's epilogue rows, all tiles
  int sI[ETPB], dI[ETPB];
#pragma unroll
  for (int tl = 0; tl < ETPB; ++tl) {
    sI[tl] = srcp[base + tl * 64 + er];
    dI[tl] = dstp[base + tl * 64 + er];
  }

#pragma unroll
  for (int i = 0; i < 8; ++i) {
    int flat = i * 256 + t;
    int n = flat >> 4, g = flat & 15;
    *reinterpret_cast<uint4*>(&Ws[n][g * 8]) =
        *reinterpret_cast<const uint4*>(&Wt[n * 128 + g * 8]);
  }
  __syncthreads();

  float stat_s = 0.f, stat_q = 0.f;

  for (int tile = 0; tile < ETPB; ++tile) {
    const size_t row0 = base + tile * 64;

    // A fragments: direct global loads
    const size_t arow = row0 + w * 16 + l16;
    short8 a[4];
#pragma unroll
    for (int ks = 0; ks < 4; ++ks)
      a[ks] = *reinterpret_cast<const short8*>(&ef[arow * 128 + ks * 32 + quad * 8]);

    float4v acc[8];
#pragma unroll
    for (int j = 0; j < 8; ++j) acc[j] = (float4v){0.f, 0.f, 0.f, 0.f};
#pragma unroll
    for (int ks = 0; ks < 4; ++ks)
#pragma unroll
      for (int j = 0; j < 8; ++j) {
        short8 b = *reinterpret_cast<const short8*>(&Ws[j * 16 + l16][ks * 32 + quad * 8]);
        acc[j] = __builtin_amdgcn_mfma_f32_16x16x32_bf16(a[ks], b, acc[j], 0, 0, 0);
      }

    if (tile) __syncthreads();   // prev tile's column loops done -> hatB free
#pragma unroll
    for (int j = 0; j < 8; ++j)
#pragma unroll
      for (int r = 0; r < 4; ++r)
        hatB[w * 16 + quad * 4 + r][j * 16 + l16] = f2bf(acc[j][r]);
    __syncthreads();

    // ---- row-major read phase (rotated sub-segments) ----
    {
      const int r = er, seg = t & 3;
      const size_t row = row0 + r;
      const int si = sI[tile], di = dI[tile];
      if (seg == 0) dstL[r] = di;
      const unsigned short* g1p = &G1[(size_t)si * 128];
      const unsigned short* g2p = &G2[(size_t)di * 128];
#pragma unroll
      for (int q2 = 0; q2 < 4; ++q2) {
        const int cc = seg * 32 + (((q2 + seg) & 3) << 3);
        uint4 mm = *reinterpret_cast<const uint4*>(&hatB[r][cc]);
        float4 b0 = *reinterpret_cast<const float4*>(&bias[cc]);
        float4 b1 = *reinterpret_cast<const float4*>(&bias[cc + 4]);
        uint4 g1 = *reinterpret_cast<const uint4*>(&g1p[cc]);
        uint4 g2 = *reinterpret_cast<const uint4*>(&g2p[cc]);
        unsigned int mw[4] = {mm.x, mm.y, mm.z, mm.w};
        unsigned int g1w[4] = {g1.x, g1.y, g1.z, g1.w};
        unsigned int g2w[4] = {g2.x, g2.y, g2.z, g2.w};
        float bv[8] = {b0.x, b0.y, b0.z, b0.w, b1.x, b1.y, b1.z, b1.w};
        unsigned int pk[4];
#pragma unroll
        for (int i = 0; i < 4; ++i) {
          float vlo = bf2f((unsigned short)(mw[i] & 0xffffu)) + bv[2 * i]
                    + bf2f((unsigned short)(g1w[i] & 0xffffu))
                    + bf2f((unsigned short)(g2w[i] & 0xffffu));
          float vhi = bf2f((unsigned short)(mw[i] >> 16)) + bv[2 * i + 1]
                    + bf2f((unsigned short)(g1w[i] >> 16))
                    + bf2f((unsigned short)(g2w[i] >> 16));
          pk[i] = (unsigned int)f2bf(vlo) | ((unsigned int)f2bf(vhi) << 16);
        }
        uint4 st; st.x = pk[0]; st.y = pk[1]; st.z = pk[2]; st.w = pk[3];
        *reinterpret_cast<uint4*>(&hat[row * 128 + cc]) = st;
        *reinterpret_cast<uint4*>(&hatB[r][cc]) = st;   // rounded write-back
      }
    }
    __syncthreads();

    // ---- unified column loop: 256 threads, 32 rows each ----
    {
      const int c = t & 127;
      const int r0c = (t >> 7) * 32;
      float s = 0.f, q = 0.f;
      float run = 0.f;
      int prev = dstL[r0c];
      for (int r = r0c; r < r0c + 32; ++r) {
        float v = bf2f(hatB[r][c]);
        if (WITH_STATS) { s += v; q += v * v; }
        int d = dstL[r];               // wave-uniform
        float sg = sigmoidf_(v);
        if (d != prev) {               // wave-uniform branch
          atomicAdd(&ssum[(size_t)prev * 128 + c], run);
          run = 0.f; prev = d;
        }
        run += sg;
      }
      atomicAdd(&ssum[(size_t)prev * 128 + c], run);
      if (WITH_STATS) { stat_s += s; stat_q += q; }
    }
  }

  if (WITH_STATS) {
    const int c = t & 127;
    atomicAdd(&stats[c], stat_s);
    atomicAdd(&stats[128 + c], stat_q);
  }
}

// ---------------------------------------------------------------------------
// Fused node GEMMs: B1,B2 (bf16 out); A1,A2,C1,C2 (fp32 out).
// Block 256 = 4 waves, 64 rows; hp tile staged in LDS once.
// ---------------------------------------------------------------------------
__global__ __launch_bounds__(256)
void ngemm6(const unsigned short* __restrict__ hp,
            const unsigned short* __restrict__ WtL,
            const float* __restrict__ B1b, const float* __restrict__ B2b,
            const float* __restrict__ A1b, const float* __restrict__ A2b,
            const float* __restrict__ C1b, const float* __restrict__ C2b,
            unsigned short* __restrict__ B1h, unsigned short* __restrict__ B2h,
            float* __restrict__ A1hp, float* __restrict__ A2hp,
            float* __restrict__ C1p, float* __restrict__ C2p)
{
  __shared__ unsigned short As[64][264];

  const int t    = threadIdx.x;
  const int w    = t >> 6;
  const int lane = t & 63;
  const int quad = lane >> 4;
  const int l16  = lane & 15;
  const size_t row0 = (size_t)blockIdx.x * 64;

#pragma unroll
  for (int i = 0; i < 8; ++i) {
    int flat = i * 256 + t;
    int r = flat >> 5, g = flat & 31;
    *reinterpret_cast<uint4*>(&As[r][g * 8]) =
        *reinterpret_cast<const uint4*>(&hp[(row0 + r) * 256 + g * 8]);
  }
  __syncthreads();

  const unsigned short* Wm[6] = {WtL, WtL + 16384, WtL + 49152, WtL + 81920,
                                 WtL + 114688, WtL + 131072};
  const int Kk[6]   = {128, 128, 256, 256, 128, 128};
  const int koff[6] = {0, 0, 0, 0, 128, 128};
  const float* bs[6] = {B1b, B2b, A1b, A2b, C1b, C2b};
  float* outf[6] = {nullptr, nullptr, A1hp, A2hp, C1p, C2p};
  unsigned short* outb[2] = {B1h, B2h};

  for (int m = 0; m < 6; ++m) {
    const unsigned short* W = Wm[m];
    const int K = Kk[m], ko = koff[m];
    float4v acc[8];
#pragma unroll
    for (int j = 0; j < 8; ++j) acc[j] = (float4v){0.f, 0.f, 0.f, 0.f};
    for (int ks = 0; ks < K / 32; ++ks) {
      short8 aa = *reinterpret_cast<const short8*>(&As[w * 16 + l16][ko + ks * 32 + quad * 8]);
#pragma unroll
      for (int j = 0; j < 8; ++j) {
        short8 b = *reinterpret_cast<const short8*>(&W[(size_t)(j * 16 + l16) * K + ks * 32 + quad * 8]);
        acc[j] = __builtin_amdgcn_mfma_f32_16x16x32_bf16(aa, b, acc[j], 0, 0, 0);
      }
    }
    const float* bb = bs[m];
    if (m < 2) {
      unsigned short* o = outb[m];
#pragma unroll
      for (int j = 0; j < 8; ++j) {
        int col = j * 16 + l16;
        float bc = bb[col];
#pragma unroll
        for (int r = 0; r < 4; ++r) {
          size_t orow = row0 + w * 16 + quad * 4 + r;
          o[orow * 128 + col] = f2bf(acc[j][r] + bc);
        }
      }
    } else {
      float* o = outf[m];
#pragma unroll
      for (int j = 0; j < 8; ++j) {
        int col = j * 16 + l16;
        float bc = bb[col];
#pragma unroll
        for (int r = 0; r < 4; ++r) {
          size_t orow = row0 + w * 16 + quad * 4 + r;
          o[orow * 128 + col] = acc[j][r] + bc;
        }
      }
    }
  }
}

// ---------------------------------------------------------------------------
// Weight prep -> bf16 transposed Wt[n][k]. Per layer (ushort offsets):
// B1@0 B2@16384 B3@32768 A1@49152 A2@81920 C1@114688 C2@131072; stride 147456.
// ---------------------------------------------------------------------------
__global__ void prep_weights(const float* __restrict__ B1, const float* __restrict__ B2,
                             const float* __restrict__ B3, const float* __restrict__ A1,
                             const float* __restrict__ A2, const float* __restrict__ C1,
                             const float* __restrict__ C2, unsigned short* __restrict__ Wt)
{
  int idx = blockIdx.x * 256 + threadIdx.x;
  if (idx >= 4 * 147456) return;
  int layer = idx / 147456;
  int o = idx - layer * 147456;
  const float* src; int K, local;
  if (o < 16384)       { src = B1 + layer * 16384; local = o;          K = 128; }
  else if (o < 32768)  { src = B2 + layer * 16384; local = o - 16384;  K = 128; }
  else if (o < 49152)  { src = B3 + layer * 16384; local = o - 32768;  K = 128; }
  else if (o < 81920)  { src = A1 + layer * 32768; local = o - 49152;  K = 256; }
  else if (o < 114688) { src = A2 + layer * 32768; local = o - 81920;  K = 256; }
  else if (o < 131072) { src = C1 + layer * 16384; local = o - 114688; K = 128; }
  else                 { src = C2 + layer * 16384; local = o - 131072; K = 128; }
  int n = local / K, k = local - n * K;
  Wt[idx] = f2bf(src[k * 128 + n]);
}

// hp_bf[n][0:128]=bf16(h), [128:256]=bf16(pc)  (initial build only)
__global__ void convert_hp(const float* __restrict__ h, const float* __restrict__ pc,
                           unsigned short* __restrict__ hp)
{
  int t = blockIdx.x * 256 + threadIdx.x;
  if (t >= N_NODES * 64) return;
  int n = t >> 6, part = t & 63;
  float4 v = (part < 32) ? reinterpret_cast<const float4*>(h)[n * 32 + part]
                         : reinterpret_cast<const float4*>(pc)[n * 32 + (part - 32)];
  ushort4 o;
  o.x = f2bf(v.x); o.y = f2bf(v.y); o.z = f2bf(v.z); o.w = f2bf(v.w);
  reinterpret_cast<ushort4*>(hp)[n * 64 + part] = o;
}

// ---------------------------------------------------------------------------
__global__ void embed_nodes_k(const int* __restrict__ idx, const float* __restrict__ table,
                              float* __restrict__ out, int M)
{
  int t = blockIdx.x * 256 + threadIdx.x;
  if (t < M * 32) {
    int r = t >> 5, c = t & 31;
    reinterpret_cast<float4*>(out)[t] =
        reinterpret_cast<const float4*>(table)[idx[r] * 32 + c];
  }
}

__global__ void embed_edges_bf(const int* __restrict__ bonds, const int* __restrict__ eidx,
                               const float* __restrict__ table,
                               unsigned short* __restrict__ out, int M)
{
  int t = blockIdx.x * 256 + threadIdx.x;
  if (t < M * 32) {
    int r = t >> 5, c = t & 31;
    float4 v = reinterpret_cast<const float4*>(table)[bonds[eidx[r]] * 32 + c];
    ushort4 o;
    o.x = f2bf(v.x); o.y = f2bf(v.y); o.z = f2bf(v.z); o.w = f2bf(v.w);
    reinterpret_cast<ushort4*>(out)[t] = o;
  }
}

// ---------------------------------------------------------------------------
// CSR build over dst + edge permutation (per-graph parallel scan).
// ---------------------------------------------------------------------------
__global__ void hist_k(const int* __restrict__ dstI, int* __restrict__ deg, int E)
{
  int e = blockIdx.x * 256 + threadIdx.x;
  if (e < E) atomicAdd(&deg[dstI[e]], 1);
}

__global__ __launch_bounds__(640)
void scan64_k(const int* __restrict__ deg, int* __restrict__ row_start,
              int* __restrict__ cursor)
{
  __shared__ int buf[640];
  const int g = blockIdx.x;
  const int t = threadIdx.x;
  const int n = g * NPG + t;
  int v = deg[n];
  buf[t] = v;
  __syncthreads();
#pragma unroll
  for (int off = 1; off < 640; off <<= 1) {
    int add = (t >= off) ? buf[t - off] : 0;
    __syncthreads();
    buf[t] += add;
    __syncthreads();
  }
  int excl = g * EPG + buf[t] - v;
  row_start[n] = excl;
  cursor[n] = excl;
  if (g == 0 && t == 0) row_start[N_NODES] = N_EDGES;
}

__global__ void fill_k(const int* __restrict__ dstI, int* __restrict__ cursor,
                       int* __restrict__ eidx, int E)
{
  int e = blockIdx.x * 256 + threadIdx.x;
  if (e < E) {
    int p = atomicAdd(&cursor[dstI[e]], 1);
    eidx[p] = e;
  }
}

__global__ void permute_sd(const int* __restrict__ eidx, const int* __restrict__ srcI,
                           const int* __restrict__ dstI, int* __restrict__ srcp,
                           int* __restrict__ dstp, int E)
{
  int e = blockIdx.x * 256 + threadIdx.x;
  if (e < E) {
    int o = eidx[e];
    srcp[e] = srcI[o];
    dstp[e] = dstI[o];
  }
}

// ---------------------------------------------------------------------------
// Single-pass gate aggregation (ssum precomputed in egemm) + fused ef update
// + hp pc-half write. One wave per node, 2 cols/lane. fp32 A2hp/C2p tables
// (bf16 tables measured slower twice: latency-bound gather, r8/r12).
// Re-zeros ssum after use (replaces per-layer memset).
// ---------------------------------------------------------------------------
template <int EF_UPD>
__global__ __launch_bounds__(256)
void gate_agg5(const unsigned short* __restrict__ hat, const int* __restrict__ row_start,
               const int* __restrict__ srcp, float* __restrict__ ssum,
               const float* __restrict__ A1hp, const float* __restrict__ A2hp,
               const float* __restrict__ C1p, const float* __restrict__ C2p,
               float* __restrict__ hraw, float* __restrict__ pc,
               unsigned short* __restrict__ ef, const float* __restrict__ ss_e,
               unsigned short* __restrict__ hp)
{
  int t = threadIdx.x;
  int node = blockIdx.x * 4 + (t >> 6);
  int lane = t & 63;
  int c = lane * 2;
  int beg = row_start[node], end = row_start[node + 1];

  float2 sv = *reinterpret_cast<const float2*>(&ssum[(size_t)node * 128 + c]);
  float2 zz; zz.x = 0.f; zz.y = 0.f;
  *reinterpret_cast<float2*>(&ssum[(size_t)node * 128 + c]) = zz;  // re-zero for next layer
  float inv0 = 1.f / (sv.x + GATE_EPS);
  float inv1 = 1.f / (sv.y + GATE_EPS);

  float2 eA, eB;
  if (EF_UPD) {
    eA = *reinterpret_cast<const float2*>(&ss_e[c]);
    eB = *reinterpret_cast<const float2*>(&ss_e[128 + c]);
  }

  float ha0 = 0.f, ha1 = 0.f, pa0 = 0.f, pa1 = 0.f;
  for (int e = beg; e < end; ++e) {
    int s = srcp[e];
    ushort2 hv = *reinterpret_cast<const ushort2*>(&hat[(size_t)e * 128 + c]);
    float hx = bf2f(hv.x), hy = bf2f(hv.y);
    float w0 = sigmoidf_(hx) * inv0;
    float w1 = sigmoidf_(hy) * inv1;
    float2 a2 = *reinterpret_cast<const float2*>(&A2hp[(size_t)s * 128 + c]);
    float2 c2 = *reinterpret_cast<const float2*>(&C2p[(size_t)s * 128 + c]);
    ha0 += w0 * a2.x; ha1 += w1 * a2.y;
    pa0 += w0 * c2.x; pa1 += w1 * c2.y;
    if (EF_UPD) {
      ushort2 ev = *reinterpret_cast<ushort2*>(&ef[(size_t)e * 128 + c]);
      float ex = bf2f(ev.x) + fmaxf(hx * eA.x + eB.x, 0.f);
      float ey = bf2f(ev.y) + fmaxf(hy * eA.y + eB.y, 0.f);
      ushort2 eo; eo.x = f2bf(ex); eo.y = f2bf(ey);
      *reinterpret_cast<ushort2*>(&ef[(size_t)e * 128 + c]) = eo;
    }
  }
  size_t ix = (size_t)node * 128 + c;
  float2 a1 = *reinterpret_cast<const float2*>(&A1hp[ix]);
  float2 c1 = *reinterpret_cast<const float2*>(&C1p[ix]);
  float2 hv; hv.x = a1.x + ha0; hv.y = a1.y + ha1;
  *reinterpret_cast<float2*>(&hraw[ix]) = hv;
  float2 pv = *reinterpret_cast<float2*>(&pc[ix]);
  pv.x += tanhf(c1.x + pa0);
  pv.y += tanhf(c1.y + pa1);
  *reinterpret_cast<float2*>(&pc[ix]) = pv;
  ushort2 ph; ph.x = f2bf(pv.x); ph.y = f2bf(pv.y);
  *reinterpret_cast<ushort2*>(&hp[(size_t)node * 256 + 128 + c]) = ph;
}

// ---------------------------------------------------------------------------
__global__ __launch_bounds__(128)
void col_stats(const float* __restrict__ x, float* __restrict__ stats, int rowsPerBlock)
{
  int d = threadIdx.x;
  size_t r0 = (size_t)blockIdx.x * rowsPerBlock;
  float s = 0.f, q = 0.f;
  for (int i = 0; i < rowsPerBlock; ++i) {
    float v = x[(r0 + i) * 128 + d];
    s += v; q += v * v;
  }
  atomicAdd(&stats[d], s);
  atomicAdd(&stats[128 + d], q);
}

__global__ void bn_finalize(const float* __restrict__ stats, const float* __restrict__ g,
                            const float* __restrict__ b, float invM, float* __restrict__ ss)
{
  int c = threadIdx.x;
  float m = stats[c] * invM;
  float v = stats[128 + c] * invM - m * m;
  float A = rsqrtf(v + BN_EPS) * g[c];
  ss[c] = A;
  ss[128 + c] = b[c] - m * A;
}

// h += relu(hraw*A+B); also writes bf16(h) into hp cols 0..127
__global__ void apply_h(float* __restrict__ dest, const float* __restrict__ xraw,
                        const float* __restrict__ ss, unsigned short* __restrict__ hp,
                        int total4)
{
  int t = blockIdx.x * 256 + threadIdx.x;
  if (t >= total4) return;
  int c4 = t & 31, n = t >> 5;
  float4 x = reinterpret_cast<const float4*>(xraw)[t];
  float4 A = reinterpret_cast<const float4*>(ss)[c4];
  float4 B = reinterpret_cast<const float4*>(ss + 128)[c4];
  float4 dv = reinterpret_cast<float4*>(dest)[t];
  dv.x += fmaxf(x.x * A.x + B.x, 0.f);
  dv.y += fmaxf(x.y * A.y + B.y, 0.f);
  dv.z += fmaxf(x.z * A.z + B.z, 0.f);
  dv.w += fmaxf(x.w * A.w + B.w, 0.f);
  reinterpret_cast<float4*>(dest)[t] = dv;
  ushort4 o;
  o.x = f2bf(dv.x); o.y = f2bf(dv.y); o.z = f2bf(dv.z); o.w = f2bf(dv.w);
  *reinterpret_cast<ushort4*>(&hp[(size_t)n * 256 + c4 * 4]) = o;
}

// ---------------------------------------------------------------------------
// fp32 GEMM kept for pc-embedding (K=16) and Whp graph-mean (MODE 2)
// ---------------------------------------------------------------------------
template <int MODE>
__global__ __launch_bounds__(256)
void gemm_k(const float* __restrict__ Xa, int Ka,
            const float* __restrict__ Xb, int Kb,
            const float* __restrict__ W,
            const float* __restrict__ bias,
            float* __restrict__ out,
            float* __restrict__ hg, float inv_nodes, int npg)
{
  __shared__ float Xs[16][68];
  __shared__ float Ws[16][128];
  __shared__ float red[8][128];

  const int t  = threadIdx.x;
  const int ty = t >> 5;
  const int tx = t & 31;
  const int row0 = blockIdx.x * 64;
  const int K = Ka + Kb;

  float acc[8][4];
#pragma unroll
  for (int i = 0; i < 8; ++i)
#pragma unroll
    for (int j = 0; j < 4; ++j) acc[i][j] = 0.f;

  const int xr = t >> 2;
  const int xk = (t & 3) << 2;
  const int wr = t >> 5;
  const int wc = tx << 2;

  for (int kk = 0; kk < K; kk += 16) {
    const float* xbase; int ldk, kloc;
    if (kk < Ka) { xbase = Xa; ldk = Ka; kloc = kk; }
    else         { xbase = Xb; ldk = Kb; kloc = kk - Ka; }
    float4 xv = *reinterpret_cast<const float4*>(
        &xbase[(size_t)(row0 + xr) * ldk + kloc + xk]);
    Xs[xk + 0][xr] = xv.x; Xs[xk + 1][xr] = xv.y;
    Xs[xk + 2][xr] = xv.z; Xs[xk + 3][xr] = xv.w;

    float4 wv0 = *reinterpret_cast<const float4*>(&W[(size_t)(kk + wr) * 128 + wc]);
    float4 wv1 = *reinterpret_cast<const float4*>(&W[(size_t)(kk + wr + 8) * 128 + wc]);
    *reinterpret_cast<float4*>(&Ws[wr][wc])     = wv0;
    *reinterpret_cast<float4*>(&Ws[wr + 8][wc]) = wv1;
    __syncthreads();

#pragma unroll
    for (int k = 0; k < 16; ++k) {
      float4 b4 = *reinterpret_cast<const float4*>(&Ws[k][wc]);
      float4 a0 = *reinterpret_cast<const float4*>(&Xs[k][ty << 3]);
      float4 a1 = *reinterpret_cast<const float4*>(&Xs[k][(ty << 3) + 4]);
      float a[8] = {a0.x, a0.y, a0.z, a0.w, a1.x, a1.y, a1.z, a1.w};
      float b[4] = {b4.x, b4.y, b4.z, b4.w};
#pragma unroll
      for (int i = 0; i < 8; ++i) {
        acc[i][0] += a[i] * b[0];
        acc[i][1] += a[i] * b[1];
        acc[i][2] += a[i] * b[2];
        acc[i][3] += a[i] * b[3];
      }
    }
    __syncthreads();
  }

  float4 bb = *reinterpret_cast<const float4*>(&bias[wc]);
  float bv[4] = {bb.x, bb.y, bb.z, bb.w};

  if (MODE == 0) {
#pragma unroll
    for (int i = 0; i < 8; ++i) {
      int r = row0 + (ty << 3) + i;
      float4 ov;
      ov.x = acc[i][0] + bv[0]; ov.y = acc[i][1] + bv[1];
      ov.z = acc[i][2] + bv[2]; ov.w = acc[i][3] + bv[3];
      *reinterpret_cast<float4*>(&out[(size_t)r * 128 + wc]) = ov;
    }
  } else {
    float csum[4] = {0, 0, 0, 0};
#pragma unroll
    for (int i = 0; i < 8; ++i) {
      csum[0] += acc[i][0]; csum[1] += acc[i][1];
      csum[2] += acc[i][2]; csum[3] += acc[i][3];
    }
#pragma unroll
    for (int j = 0; j < 4; ++j) red[ty][wc + j] = csum[j];
    __syncthreads();
    if (ty == 0) {
      int g = row0 / npg;
#pragma unroll
      for (int j = 0; j < 4; ++j) {
        float s = 0;
#pragma unroll
        for (int q = 0; q < 8; ++q) s += red[q][wc + j];
        atomicAdd(&hg[(size_t)g * 128 + wc + j], (s + 64.f * bv[j]) * inv_nodes);
      }
    }
  }
}

// ---------------------------------------------------------------------------
__global__ __launch_bounds__(256)
void po_gemm(const float* __restrict__ pc, const float* __restrict__ w,
             const float* __restrict__ b, float* __restrict__ po)
{
  __shared__ float pcs[16][128];
  __shared__ float wl[128][16];
  int t = threadIdx.x;
  int n0 = blockIdx.x * 16;
  for (int i = t; i < 512; i += 256) {
    int r = i >> 5, c = (i & 31) << 2;
    *reinterpret_cast<float4*>(&pcs[r][c]) =
        *reinterpret_cast<const float4*>(&pc[(size_t)(n0 + r) * 128 + c]);
  }
  for (int i = t; i < 512; i += 256) {
    int r = i >> 2, c = (i & 3) << 2;
    *reinterpret_cast<float4*>(&wl[r][c]) =
        *reinterpret_cast<const float4*>(&w[r * 16 + c]);
  }
  __syncthreads();
  int i = t >> 4, j = t & 15;
  float acc = b[j];
  for (int k = 0; k < 128; ++k) acc += pcs[i][k] * wl[k][j];
  po[(size_t)(n0 + i) * 16 + j] = acc;
}

__global__ __launch_bounds__(256)
void pe_norm(float* __restrict__ po)
{
  int g = blockIdx.x;
  int t = threadIdx.x;
  int j = t & 15, grp = t >> 4;
  __shared__ float red[16][16];
  __shared__ float mean_s[16];
  __shared__ float nrm_s[16];
  size_t bse = (size_t)g * NPG * 16;
  float s = 0.f;
  for (int i = grp; i < NPG; i += 16) s += po[bse + i * 16 + j];
  red[grp][j] = s;
  __syncthreads();
  if (grp == 0) {
    float m = 0.f;
    for (int q = 0; q < 16; ++q) m += red[q][j];
    mean_s[j] = m / NPG;
  }
  __syncthreads();
  float m = mean_s[j];
  float q2 = 0.f;
  for (int i = grp; i < NPG; i += 16) {
    float c = po[bse + i * 16 + j] - m;
    q2 += c * c;
  }
  red[grp][j] = q2;
  __syncthreads();
  if (grp == 0) {
    float v = 0.f;
    for (int q = 0; q < 16; ++q) v += red[q][j];
    nrm_s[j] = sqrtf(v);
  }
  __syncthreads();
  float inv = 1.f / nrm_s[j];
  for (int i = grp; i < NPG; i += 16) {
    size_t ix = bse + i * 16 + j;
    po[ix] = (po[ix] - m) * inv;
  }
}

__global__ __launch_bounds__(256)
void mlp_head(const float* __restrict__ hg,
              const float* __restrict__ w0, const float* __restrict__ b0,
              const float* __restrict__ w1, const float* __restrict__ b1,
              const float* __restrict__ w2, const float* __restrict__ b2,
              float* __restrict__ out)
{
  __shared__ float hs[64 * 128];
  __shared__ float y0[64 * 64];
  __shared__ float y1[64 * 32];
  int t = threadIdx.x;
  for (int i = t; i < 64 * 128 / 4; i += 256)
    reinterpret_cast<float4*>(hs)[i] = reinterpret_cast<const float4*>(hg)[i];
  __syncthreads();
  for (int o = t; o < 64 * 64; o += 256) {
    int i = o >> 6, j = o & 63;
    float a = b0[j];
    for (int k = 0; k < 128; ++k) a += hs[i * 128 + k] * w0[k * 64 + j];
    y0[o] = fmaxf(a, 0.f);
  }
  __syncthreads();
  for (int o = t; o < 64 * 32; o += 256) {
    int i = o >> 5, j = o & 31;
    float a = b1[j];
    for (int k = 0; k < 64; ++k) a += y0[i * 64 + k] * w1[k * 32 + j];
    y1[o] = fmaxf(a, 0.f);
  }
  __syncthreads();
  if (t < 64) {
    float a = b2[0];
    for (int k = 0; k < 32; ++k) a += y1[t * 32 + k] * w2[k];
    out[t] = a;
  }
}

__global__ void fill_sentinel(float* out, int n, float v)
{
  int t = blockIdx.x * 256 + threadIdx.x;
  if (t < n) out[t] = v;
}

// ---------------------------------------------------------------------------
extern "C" void kernel_launch(void* const* d_in, const int* in_sizes, int n_in,
                              void* d_out, int out_size, void* d_ws, size_t ws_size,
                              hipStream_t stream)
{
  const int*   h_atoms = (const int*)d_in[0];
  const int*   e_bonds = (const int*)d_in[1];
  const int*   srcI    = (const int*)d_in[2];
  const int*   dstI    = (const int*)d_in[3];
  const float* p_in    = (const float*)d_in[5];
  const float* W_emb_h = (const float*)d_in[6];
  const float* W_emb_p = (const float*)d_in[7];
  const float* b_emb_p = (const float*)d_in[8];
  const float* W_emb_e = (const float*)d_in[9];
  const float* A1_w = (const float*)d_in[10];
  const float* A1_b = (const float*)d_in[11];
  const float* A2_w = (const float*)d_in[12];
  const float* A2_b = (const float*)d_in[13];
  const float* B1_w = (const float*)d_in[14];
  const float* B1_b = (const float*)d_in[15];
  const float* B2_w = (const float*)d_in[16];
  const float* B2_b = (const float*)d_in[17];
  const float* B3_w = (const float*)d_in[18];
  const float* B3_b = (const float*)d_in[19];
  const float* C1_w = (const float*)d_in[20];
  const float* C1_b = (const float*)d_in[21];
  const float* C2_w = (const float*)d_in[22];
  const float* C2_b = (const float*)d_in[23];
  const float* bn_h_g = (const float*)d_in[24];
  const float* bn_h_b = (const float*)d_in[25];
  const float* bn_e_g = (const float*)d_in[26];
  const float* bn_e_b = (const float*)d_in[27];
  const float* p_out_w = (const float*)d_in[28];
  const float* p_out_b = (const float*)d_in[29];
  const float* Whp_w   = (const float*)d_in[30];
  const float* Whp_b   = (const float*)d_in[31];
  const float* mlp_w0  = (const float*)d_in[32];
  const float* mlp_b0  = (const float*)d_in[33];
  const float* mlp_w1  = (const float*)d_in[34];
  const float* mlp_b1  = (const float*)d_in[35];
  const float* mlp_w2  = (const float*)d_in[36];
  const float* mlp_b2  = (const float*)d_in[37];

  static void* pool_ptr = nullptr;
  if (!pool_ptr) {
    if (hipGetSymbolAddress(&pool_ptr, HIP_SYMBOL(g_pool)) != hipSuccess || !pool_ptr) {
      fill_sentinel<<<dim3(1), dim3(256), 0, stream>>>((float*)d_out, out_size, 12345.0f);
      return;
    }
  }

  float* fbase = (float*)pool_ptr;
  size_t fo = 0;
  auto carvef = [&](size_t nf) { float* r = fbase + fo; fo += nf; return r; };
  float* h    = carvef((size_t)N_NODES * DH);
  float* pc   = carvef((size_t)N_NODES * DH);
  float* A1hp = carvef((size_t)N_NODES * DH);
  float* A2hp = carvef((size_t)N_NODES * DH);
  float* C1p  = carvef((size_t)N_NODES * DH);
  float* C2p  = carvef((size_t)N_NODES * DH);
  float* hraw = carvef((size_t)N_NODES * DH);
  float* ssum = carvef((size_t)N_NODES * DH);
  float* po   = carvef((size_t)N_NODES * 16);
  float* hg   = carvef(NGRAPH * 128);
  float* estats = carvef(256);
  float* hstats = carvef(256);
  float* ss_e   = carvef(256);
  float* ss_h   = carvef(256);

  unsigned short* ubase = (unsigned short*)(fbase + fo);
  unsigned short* ef_bf  = ubase;
  unsigned short* hat_bf = ef_bf + (size_t)N_EDGES * DH;
  unsigned short* hp_bf  = hat_bf + (size_t)N_EDGES * DH;
  unsigned short* b1_bf  = hp_bf + (size_t)N_NODES * 256;
  unsigned short* b2_bf  = b1_bf + (size_t)N_NODES * DH;
  unsigned short* Wt_bf  = b2_bf + (size_t)N_NODES * DH;
  int* ibase = (int*)(Wt_bf + 4 * 147456);
  int* deg       = ibase;
  int* row_start = deg + N_NODES;
  int* cursor    = row_start + (N_NODES + 3);
  int* eidx      = cursor + N_NODES;
  int* srcp      = eidx + N_EDGES;
  int* dstp      = srcp + N_EDGES;

  dim3 b256(256);

  // --- weight prep ---
  prep_weights<<<dim3((4 * 147456 + 255) / 256), b256, 0, stream>>>(
      B1_w, B2_w, B3_w, A1_w, A2_w, C1_w, C2_w, Wt_bf);

  // --- CSR over dst + permutation (per-graph parallel scan) ---
  hipMemsetAsync(deg, 0, N_NODES * sizeof(int), stream);
  hipMemsetAsync(ssum, 0, (size_t)N_NODES * DH * sizeof(float), stream);
  hist_k<<<dim3((N_EDGES + 255) / 256), b256, 0, stream>>>(dstI, deg, N_EDGES);
  scan64_k<<<dim3(NGRAPH), dim3(640), 0, stream>>>(deg, row_start, cursor);
  fill_k<<<dim3((N_EDGES + 255) / 256), b256, 0, stream>>>(dstI, cursor, eidx, N_EDGES);
  permute_sd<<<dim3((N_EDGES + 255) / 256), b256, 0, stream>>>(eidx, srcI, dstI, srcp, dstp, N_EDGES);

  // --- embeddings (edges in CSR order) ---
  embed_nodes_k<<<dim3((N_NODES * 32 + 255) / 256), b256, 0, stream>>>(h_atoms, W_emb_h, h, N_NODES);
  embed_edges_bf<<<dim3((N_EDGES * 32 + 255) / 256), b256, 0, stream>>>(
      e_bonds, eidx, W_emb_e, ef_bf, N_EDGES);
  gemm_k<0><<<dim3(N_NODES / 64), b256, 0, stream>>>(
      p_in, 16, nullptr, 0, W_emb_p, b_emb_p, pc, nullptr, 0.f, NPG);
  convert_hp<<<dim3(N_NODES * 64 / 256), b256, 0, stream>>>(h, pc, hp_bf);

  const dim3 gNode64(N_NODES / 64), gEdge(N_EDGES / (64 * ETPB));

  // --- layers ---
  for (int l = 0; l < NLAYERS; ++l) {
    const unsigned short* WtL = Wt_bf + (size_t)l * 147456;
    const unsigned short* WtB3 = WtL + 32768;
    const bool last = (l == NLAYERS - 1);

    ngemm6<<<gNode64, b256, 0, stream>>>(hp_bf, WtL,
        B1_b + l * 128, B2_b + l * 128, A1_b + l * 128, A2_b + l * 128,
        C1_b + l * 128, C2_b + l * 128, b1_bf, b2_bf, A1hp, A2hp, C1p, C2p);

    if (!last) {
      hipMemsetAsync(estats, 0, 256 * sizeof(float), stream);
      egemm<1><<<gEdge, b256, 0, stream>>>(ef_bf, WtB3, B3_b + l * 128, hat_bf,
          srcp, dstp, b1_bf, b2_bf, estats, ssum);
      bn_finalize<<<dim3(1), dim3(128), 0, stream>>>(
          estats, bn_e_g + l * 128, bn_e_b + l * 128, 1.f / N_EDGES, ss_e);
      gate_agg5<1><<<dim3(N_NODES / 4), b256, 0, stream>>>(
          hat_bf, row_start, srcp, ssum, A1hp, A2hp, C1p, C2p, hraw, pc,
          ef_bf, ss_e, hp_bf);
    } else {
      egemm<0><<<gEdge, b256, 0, stream>>>(ef_bf, WtB3, B3_b + l * 128, hat_bf,
          srcp, dstp, b1_bf, b2_bf, nullptr, ssum);
      gate_agg5<0><<<dim3(N_NODES / 4), b256, 0, stream>>>(
          hat_bf, row_start, srcp, ssum, A1hp, A2hp, C1p, C2p, hraw, pc,
          nullptr, nullptr, hp_bf);
    }

    hipMemsetAsync(hstats, 0, 256 * sizeof(float), stream);
    col_stats<<<dim3(128), dim3(128), 0, stream>>>(hraw, hstats, N_NODES / 128);
    bn_finalize<<<dim3(1), dim3(128), 0, stream>>>(
        hstats, bn_h_g + l * 128, bn_h_b + l * 128, 1.f / N_NODES, ss_h);

    apply_h<<<dim3(N_NODES * 32 / 256), b256, 0, stream>>>(
        h, hraw, ss_h, hp_bf, N_NODES * 32);
  }

  // --- PE output head ---
  po_gemm<<<dim3(N_NODES / 16), b256, 0, stream>>>(pc, p_out_w, p_out_b, po);
  pe_norm<<<dim3(NGRAPH), b256, 0, stream>>>(po);

  hipMemsetAsync(hg, 0, NGRAPH * 128 * sizeof(float), stream);
  gemm_k<2><<<dim3(N_NODES / 64), b256, 0, stream>>>(
      h, 128, po, 16, Whp_w, Whp_b, nullptr, hg, 1.f / NPG, NPG);

  mlp_head<<<dim3(1), b256, 0, stream>>>(
      hg, mlp_w0, mlp_b0, mlp_w1, mlp_b1, mlp_w2, mlp_b2, (float*)d_out);
}